// Round 9
// baseline (317.802 us; speedup 1.0000x reference)
//
#include <hip/hip_runtime.h>
#include <hip/hip_bf16.h>
#include <math.h>

// Problem: B=4, N=40962, K=7, C=128
//   sig[b,m]     = sigmoid( sum_d tanh((query[b,m,:]@W1)[d] + b1[d]) * V[d] + bV )
//   score[b,n,k] = sig[b, neigh[n,k]]
//   attn         = score / sum_k score
//   context[b,n] = sum_k attn[b,n,k] * values[b, neigh[n,k], :]
//
// Pipeline:
//   k0_wconv : W1 -> fragment-ordered split-bf16 planes (64KB, one-shot)
//   k1_mfma_conv : 2 contiguous 64-row tiles per block, BOTH tiles' query
//                  loads issued up front (64 VGPR of loads in flight before
//                  any wait) -> Little's-law fix for the 0.5-1.5 TB/s query
//                  stream seen in R5/R6 (FETCH exactly = needed bytes, all
//                  pipes idle, occupancy-insensitive). values->bf16 conv
//                  folded per-tile (loads at tile start, pack after MFMA).
//                  NOTE: R7's persistent while(true) variant hit two
//                  container failures; this is the same mechanism with
//                  conventional control flow (no persistence, no loop).
//   k2_gather_bf16 : bf16 gather + normalize, XCD-batch affinity, 2 rows/group
// bf16 values essential (R3: fp32 gather = 95us, FETCH 239MB, L3 thrash).

#define CDIM 128
#define KNEIGH 7

typedef __attribute__((ext_vector_type(8))) short bf16x8;
typedef __attribute__((ext_vector_type(4))) short bf16x4;
typedef __attribute__((ext_vector_type(4))) float floatx4;

__device__ inline short f2bf(float x) {
    union { float f; unsigned u; } v; v.f = x;
    unsigned r = (v.u + 0x7fff + ((v.u >> 16) & 1)) >> 16;   // RNE
    return (short)r;
}
__device__ inline float bf2f(short h) {
    union { float f; unsigned u; } v;
    v.u = ((unsigned)(unsigned short)h) << 16; return v.f;
}
__device__ inline float fast_tanh(float x) {
    float e = __expf(2.0f * x);          // inf-safe: e=inf -> 1, e=0 -> -1
    return 1.0f - 2.0f / (e + 1.0f);
}

// ---------------- Kernel 0: W1 -> fragment-ordered split-bf16 planes -------
// plane[((t8*4+ks)*64 + lane)*8 + j] = W1[(ks*32+(lane>>4)*8+j)][t8*16+(lane&15)]
__global__ __launch_bounds__(256) void k0_wconv(
    const float* __restrict__ W1,   // (128,128) [c][d]
    short* __restrict__ whi,        // 16384 shorts (32 KB)
    short* __restrict__ wlo)        // 16384 shorts (32 KB)
{
    const int idx  = blockIdx.x * 256 + threadIdx.x;   // 2048 fragment tuples
    const int lane = idx & 63;
    const int ksf  = (idx >> 6) & 3;
    const int t8   = idx >> 8;
    const int m = lane & 15, q = lane >> 4;
    const int d  = t8 * 16 + m;
    const int c0 = ksf * 32 + q * 8;
    bf16x8 hv, lv;
#pragma unroll
    for (int j = 0; j < 8; ++j) {
        float w = W1[(size_t)(c0 + j) * CDIM + d];
        short h = f2bf(w);
        hv[j] = h;
        lv[j] = f2bf(w - bf2f(h));
    }
    *((bf16x8*)whi + idx) = hv;
    *((bf16x8*)wlo + idx) = lv;
}

// ---------------- Kernel 1 helpers ----------------------------------------
__device__ __forceinline__ void load_q(float4 (&buf)[8],
                                       const float* __restrict__ query,
                                       long tile, int wv, int m, int q,
                                       int totalRows) {
    long r = tile * 64 + wv * 16 + m;
    if (r >= totalRows) r = totalRows - 1;   // clamped rows discarded later
    const float4* qp = (const float4*)(query + (size_t)r * CDIM) + q * 2;
#pragma unroll
    for (int ks = 0; ks < 4; ++ks) {
        buf[ks * 2]     = qp[ks * 8];
        buf[ks * 2 + 1] = qp[ks * 8 + 1];
    }
}

__device__ __forceinline__ void compute_tile(
    const float4 (&qb)[8], long tile,
    const short* Wh, const short* Wl,
    const float (&b1v)[8], const float (&Vv)[8], float bVv,
    const float* __restrict__ values, float* __restrict__ sig,
    short* __restrict__ vbf, int totalRows, int doConv,
    int wv, int lane, int m, int q, int t)
{
    // ---- issue this tile's values-conv loads early (hidden under MFMA) ---
    float4 vva[4], vvb[4];
    bool cok[4];
    const int nChunks = totalRows * 16;           // bf16x8 chunks
    const int cBase = (int)tile * 1024 + t;
    if (doConv) {
#pragma unroll
        for (int i = 0; i < 4; ++i) {
            int c = cBase + i * 256;
            cok[i] = c < nChunks;
            const float4* vp = (const float4*)values + (size_t)(cok[i] ? c : 0) * 2;
            vva[i] = vp[0];
            vvb[i] = vp[1];
        }
    }

    floatx4 acc[8];
#pragma unroll
    for (int t8 = 0; t8 < 8; ++t8) acc[t8] = (floatx4){0.f, 0.f, 0.f, 0.f};

#pragma unroll
    for (int ks = 0; ks < 4; ++ks) {
        float4 qa = qb[ks * 2];
        float4 qc = qb[ks * 2 + 1];
        float qs[8] = {qa.x, qa.y, qa.z, qa.w, qc.x, qc.y, qc.z, qc.w};
        bf16x8 ah, al;
#pragma unroll
        for (int j = 0; j < 8; ++j) {
            short h = f2bf(qs[j]);
            ah[j] = h;
            al[j] = f2bf(qs[j] - bf2f(h));
        }
#pragma unroll
        for (int t8 = 0; t8 < 8; ++t8) {
            bf16x8 bh = *(const bf16x8*)&Wh[((t8 * 4 + ks) * 64 + lane) * 8];
            bf16x8 bl = *(const bf16x8*)&Wl[((t8 * 4 + ks) * 64 + lane) * 8];
            acc[t8] = __builtin_amdgcn_mfma_f32_16x16x32_bf16(ah, bh, acc[t8], 0, 0, 0);
            acc[t8] = __builtin_amdgcn_mfma_f32_16x16x32_bf16(al, bh, acc[t8], 0, 0, 0);
            acc[t8] = __builtin_amdgcn_mfma_f32_16x16x32_bf16(ah, bl, acc[t8], 0, 0, 0);
        }
    }

    // ---- epilogue: tanh, dot-V, 16-lane reduce, sigmoid ------------------
    const long rowBase = tile * 64 + wv * 16;
    {
        float p[4] = {0.f, 0.f, 0.f, 0.f};
#pragma unroll
        for (int t8 = 0; t8 < 8; ++t8) {
#pragma unroll
            for (int i = 0; i < 4; ++i) {
                float x = acc[t8][i] + b1v[t8];
                p[i] += fast_tanh(x) * Vv[t8];
            }
        }
#pragma unroll
        for (int mask = 1; mask <= 8; mask <<= 1) {
#pragma unroll
            for (int i = 0; i < 4; ++i) p[i] += __shfl_xor(p[i], mask, 64);
        }
        if (m == 0) {
#pragma unroll
            for (int i = 0; i < 4; ++i) {
                long r = rowBase + q * 4 + i;   // D row = q*4 + reg
                if (r < totalRows)
                    sig[r] = 1.0f / (1.0f + __expf(-(p[i] + bVv)));
            }
        }
    }

    // ---- pack + store this tile's values bf16 chunks ---------------------
    if (doConv) {
#pragma unroll
        for (int i = 0; i < 4; ++i) {
            if (cok[i]) {
                float4 a = vva[i], b = vvb[i];
                bf16x8 o;
                o[0] = f2bf(a.x); o[1] = f2bf(a.y); o[2] = f2bf(a.z); o[3] = f2bf(a.w);
                o[4] = f2bf(b.x); o[5] = f2bf(b.y); o[6] = f2bf(b.z); o[7] = f2bf(b.w);
                ((bf16x8*)vbf)[cBase + i * 256] = o;
            }
        }
    }
}

// ---------------- Kernel 1: 2-tile pipelined MFMA + fused values conv ------
// Each block: tiles 2*bid and 2*bid+1 (contiguous, 64 rows each). Both
// tiles' query loads issued before any compute -> deep VMEM pipeline.
// W planes in LDS (64KB -> 2 blocks/CU), staged once per block.
__global__ __launch_bounds__(256, 2) void k1_mfma_conv(
    const float* __restrict__ query,   // (totalRows, 128)
    const short* __restrict__ whi,     // fragment-ordered hi plane
    const short* __restrict__ wlo,     // fragment-ordered lo plane
    const float* __restrict__ b1,      // (128)
    const float* __restrict__ V,       // (128)
    const float* __restrict__ bV,      // (1)
    const float* __restrict__ values,  // (totalRows, 128)
    float* __restrict__ sig,           // (totalRows)
    short* __restrict__ vbf,           // (totalRows, 128) bf16 out (or null)
    int totalRows, int doConv)
{
    __shared__ short Wh[16384];   // 32 KB hi plane (linear, frag-ordered)
    __shared__ short Wl[16384];   // 32 KB lo plane

    const int t    = threadIdx.x;
    const int wv   = t >> 6;
    const int lane = t & 63;
    const int m    = lane & 15;
    const int q    = lane >> 4;

    // ---- stage W planes: 2048 16B-chunks per plane, 8 per thread ---------
#pragma unroll
    for (int i = 0; i < 8; ++i) {
        const int c = t + i * 256;
        *(bf16x8*)&Wh[c * 8] = ((const bf16x8*)whi)[c];
        *(bf16x8*)&Wl[c * 8] = ((const bf16x8*)wlo)[c];
    }
    __syncthreads();

    const int nTiles = (totalRows + 63) >> 6;
    const long tile0 = (long)blockIdx.x * 2;
    if (tile0 >= nTiles) return;          // uniform (after barrier)
    const long tile1 = tile0 + 1;
    const bool has1 = tile1 < nTiles;

    // ---- issue BOTH tiles' query loads before any compute ----------------
    float4 qA[8], qB[8];
    load_q(qA, query, tile0, wv, m, q, totalRows);
    if (has1) load_q(qB, query, tile1, wv, m, q, totalRows);

    float b1v[8], Vv[8];
#pragma unroll
    for (int t8 = 0; t8 < 8; ++t8) {
        int d = t8 * 16 + m;
        b1v[t8] = b1[d];
        Vv[t8]  = V[d];
    }
    const float bVv = bV[0];

    compute_tile(qA, tile0, Wh, Wl, b1v, Vv, bVv, values, sig, vbf,
                 totalRows, doConv, wv, lane, m, q, t);
    if (has1)
        compute_tile(qB, tile1, Wh, Wl, b1v, Vv, bVv, values, sig, vbf,
                     totalRows, doConv, wv, lane, m, q, t);
}

// ---------------- Kernel 2a: bf16 gather, XCD-batch affinity ---------------
// B=4 assumed. bid&7 = XCD (round-robin dispatch heuristic); XCD pair
// (2k,2k+1) owns batch k. 2 rows per 32-lane group: 14 outstanding 8B
// gathers to hide latency.
__global__ __launch_bounds__(256) void k2_gather_bf16(
    const short* __restrict__ vbf,     // (B*N, 128) bf16
    const int*   __restrict__ neigh,   // (N, 7)
    const float* __restrict__ sig,     // (B*N)
    float* __restrict__ context,       // (B*N, 128)
    float* __restrict__ score,         // (B*N, 7)
    int Nv, int blocksPerBatch)
{
    const int t   = threadIdx.x;
    const int bid = blockIdx.x;
    const int xcd = bid & 7;
    const int b   = xcd >> 1;
    const int nb  = ((bid >> 3) << 1) | (xcd & 1);
    if (nb >= blocksPerBatch) return;
    const int n0 = nb * 16 + ((t >> 5) << 1);
    if (n0 >= Nv) return;
    const bool has1 = (n0 + 1) < Nv;
    const int lane = t & 31;
    const size_t rowOffB = (size_t)b * Nv;

    const int* np0 = neigh + (size_t)n0 * KNEIGH;
    const int* np1 = np0 + KNEIGH;

    int   idx0[KNEIGH], idx1[KNEIGH];
    float s0[KNEIGH],   s1[KNEIGH];
    float ssum0 = 0.f, ssum1 = 0.f;
#pragma unroll
    for (int k = 0; k < KNEIGH; ++k) idx0[k] = np0[k];
#pragma unroll
    for (int k = 0; k < KNEIGH; ++k) idx1[k] = has1 ? np1[k] : idx0[k];
#pragma unroll
    for (int k = 0; k < KNEIGH; ++k) { s0[k] = sig[rowOffB + idx0[k]]; ssum0 += s0[k]; }
#pragma unroll
    for (int k = 0; k < KNEIGH; ++k) { s1[k] = sig[rowOffB + idx1[k]]; ssum1 += s1[k]; }
    const float inv0 = 1.0f / ssum0;
    const float inv1 = 1.0f / ssum1;

    float a0 = 0.f, a1 = 0.f, a2 = 0.f, a3 = 0.f;
    float c0 = 0.f, c1 = 0.f, c2 = 0.f, c3 = 0.f;
#pragma unroll
    for (int k = 0; k < KNEIGH; ++k) {
        bf16x4 v0 = ((const bf16x4*)(vbf + (rowOffB + idx0[k]) * CDIM))[lane];
        bf16x4 v1 = ((const bf16x4*)(vbf + (rowOffB + idx1[k]) * CDIM))[lane];
        float w0 = s0[k] * inv0;
        float w1 = s1[k] * inv1;
        a0 += w0 * bf2f(v0[0]); a1 += w0 * bf2f(v0[1]);
        a2 += w0 * bf2f(v0[2]); a3 += w0 * bf2f(v0[3]);
        c0 += w1 * bf2f(v1[0]); c1 += w1 * bf2f(v1[1]);
        c2 += w1 * bf2f(v1[2]); c3 += w1 * bf2f(v1[3]);
    }
    const size_t g0 = rowOffB + n0;
    floatx4 r0 = (floatx4){a0, a1, a2, a3};
    __builtin_nontemporal_store(r0, (floatx4*)context + g0 * (CDIM / 4) + lane);
    if (has1) {
        floatx4 r1 = (floatx4){c0, c1, c2, c3};
        __builtin_nontemporal_store(r1, (floatx4*)context + (g0 + 1) * (CDIM / 4) + lane);
    }

    // score = s[k] via register select (bit-identical to re-gathering sig).
    if (lane < KNEIGH) {
        float sv = (lane == 1) ? s0[1] : (lane == 2) ? s0[2] : (lane == 3) ? s0[3]
                 : (lane == 4) ? s0[4] : (lane == 5) ? s0[5] : (lane == 6) ? s0[6]
                 : s0[0];
        __builtin_nontemporal_store(sv, score + g0 * KNEIGH + lane);
    } else if (lane >= 8 && lane < 8 + KNEIGH && has1) {
        const int k = lane - 8;
        float sv = (k == 1) ? s1[1] : (k == 2) ? s1[2] : (k == 3) ? s1[3]
                 : (k == 4) ? s1[4] : (k == 5) ? s1[5] : (k == 6) ? s1[6]
                 : s1[0];
        __builtin_nontemporal_store(sv, score + (g0 + 1) * KNEIGH + k);
    }
}

// ---------------- Kernel 2b: fp32 fallback (ws too small / B!=4) ----------
__global__ __launch_bounds__(256) void k2_gather_fp32(
    const float* __restrict__ values,
    const int*   __restrict__ neigh,
    const float* __restrict__ sig,
    float* __restrict__ context,
    float* __restrict__ score,
    int Bv, int Nv)
{
    const int t    = threadIdx.x;
    const int g    = blockIdx.x * 8 + (t >> 5);
    const int lane = t & 31;
    const int total = Bv * Nv;
    if (g >= total) return;
    const int b = g / Nv;
    const int n = g - b * Nv;

    const int* np = neigh + (size_t)n * KNEIGH;
    const size_t rowOffB = (size_t)b * Nv;

    int   idx[KNEIGH];
    float s[KNEIGH];
    float ssum = 0.f;
#pragma unroll
    for (int k = 0; k < KNEIGH; ++k) {
        idx[k] = np[k];
        s[k]   = sig[rowOffB + idx[k]];
        ssum  += s[k];
    }
    const float inv = 1.0f / ssum;

    floatx4 acc = (floatx4){0.f, 0.f, 0.f, 0.f};
#pragma unroll
    for (int k = 0; k < KNEIGH; ++k) {
        const floatx4* vp = (const floatx4*)(values + (rowOffB + idx[k]) * CDIM);
        floatx4 v4 = vp[lane];
        float a = s[k] * inv;
        acc += a * v4;
    }
    __builtin_nontemporal_store(acc, (floatx4*)context + (size_t)g * (CDIM / 4) + lane);

    if (lane < KNEIGH) {
        float sv = (lane == 1) ? s[1] : (lane == 2) ? s[2] : (lane == 3) ? s[3]
                 : (lane == 4) ? s[4] : (lane == 5) ? s[5] : (lane == 6) ? s[6]
                 : s[0];
        __builtin_nontemporal_store(sv, score + (size_t)g * KNEIGH + lane);
    }
}

extern "C" void kernel_launch(void* const* d_in, const int* in_sizes, int n_in,
                              void* d_out, int out_size, void* d_ws, size_t ws_size,
                              hipStream_t stream) {
    const float* query  = (const float*)d_in[0];
    const float* values = (const float*)d_in[1];
    const int*   neigh  = (const int*)d_in[2];
    const float* W1     = (const float*)d_in[3];
    const float* b1     = (const float*)d_in[4];
    const float* V      = (const float*)d_in[5];
    const float* bV     = (const float*)d_in[6];

    const int N = in_sizes[2] / KNEIGH;            // 40962
    const int totalRows = in_sizes[0] / CDIM;      // B*N
    const int B = totalRows / N;                   // 4

    float* context = (float*)d_out;                            // (B*N,128)
    float* score   = (float*)d_out + (size_t)totalRows * CDIM; // (B*N,7)

    // workspace: [whi 32KB][wlo 32KB][sig][vbf]
    short* whi = (short*)d_ws;
    short* wlo = whi + 16384;
    const size_t wOff = 65536;
    float* sig = (float*)((char*)d_ws + wOff);
    size_t sigBytes = (size_t)totalRows * 4;
    size_t vbfOff   = (wOff + sigBytes + 1023) & ~(size_t)1023;
    size_t needBytes = vbfOff + (size_t)totalRows * CDIM * 2;
    const bool useBf16 = (ws_size >= needBytes) && (B == 4);
    short* vbf = (short*)((char*)d_ws + vbfOff);

    hipLaunchKernelGGL(k0_wconv, dim3(8), dim3(256), 0, stream, W1, whi, wlo);

    int nTiles = (totalRows + 63) / 64;            // 2561
    int g1 = (nTiles + 1) / 2;                     // 1281 blocks
    hipLaunchKernelGGL(k1_mfma_conv, dim3(g1), dim3(256), 0, stream,
                       query, whi, wlo, b1, V, bV, values, sig, vbf,
                       totalRows, useBf16 ? 1 : 0);

    if (useBf16) {
        int blocksPerBatch = (N + 15) / 16;                // 2561
        int g2 = 8 * ((blocksPerBatch + 1) / 2);           // 10248
        hipLaunchKernelGGL(k2_gather_bf16, dim3(g2), dim3(256), 0, stream,
                           vbf, neigh, sig, context, score, N, blocksPerBatch);
    } else {
        int g2 = (totalRows + 7) / 8;
        hipLaunchKernelGGL(k2_gather_fp32, dim3(g2), dim3(256), 0, stream,
                           values, neigh, sig, context, score, B, N);
    }
}